// Round 9
// baseline (347.044 us; speedup 1.0000x reference)
//
#include <hip/hip_runtime.h>

#define NNODES 65536
#define FIN 1024
#define NEDGES 2097152
#define NB 64
#define G 256                 // buckets = dst>>8
#define CH (NEDGES / G)       // 8192 edges per scatter block
#define CAPR 96               // slots per (bucket, block) run in tmp
#define CAPB 9216             // slots per bucket in csr (8192 + 11 sigma)
#define SCAP 10240            // LDS staging capacity in ksortD

// ============ kernel 1: fused  h1 = x@W1 (unscaled)  ∪  padded-slot scatter ============
// gemm blocks 0..255: 256 rows each, 1 row/thread, W via scalar loads (wave-uniform),
//   x staged coalesced into LDS (stride 33 -> conflict-free b32 reads).
// scatter blocks 256..511: LDS cursors from 0, direct writes into fixed 96-slot runs.
__global__ __launch_bounds__(256) void kmain(const float* __restrict__ x, const float* __restrict__ W1,
                                             float* __restrict__ h1, const int* __restrict__ src,
                                             const int* __restrict__ dst, const float* __restrict__ ew,
                                             int2* __restrict__ tmp, int* __restrict__ counts) {
  __shared__ float sx[256 * 33];            // 33.8 KB
  __shared__ int cursor[256];
  const int t = threadIdx.x;
  if (blockIdx.x < 256) {
    // ---------------- GEMM ----------------
    const int row0 = blockIdx.x * 256;
    float acc[16];
#pragma unroll
    for (int j = 0; j < 16; ++j) acc[j] = 0.f;
    for (int ch = 0; ch < 32; ++ch) {
      const int c0 = ch * 32;
#pragma unroll
      for (int i = 0; i < 8; ++i) {         // stage 256 rows x 32 k, coalesced float4
        const int v = t + i * 256;
        const int rr = v >> 3, k4 = v & 7;
        const float4 xv = *(const float4*)(x + (size_t)(row0 + rr) * FIN + c0 + k4 * 4);
        const int a = rr * 33 + k4 * 4;
        sx[a] = xv.x; sx[a + 1] = xv.y; sx[a + 2] = xv.z; sx[a + 3] = xv.w;
      }
      __syncthreads();
      const int cc0 = __builtin_amdgcn_readfirstlane(c0);
#pragma unroll 4
      for (int kk = 0; kk < 32; ++kk) {
        const float xv = sx[t * 33 + kk];   // bank (t+kk)%32 -> 2 lanes/bank, free
        const float* __restrict__ wk = W1 + (size_t)(cc0 + kk) * 16;   // uniform -> s_load
#pragma unroll
        for (int j = 0; j < 16; ++j) acc[j] = fmaf(xv, wk[j], acc[j]);
      }
      __syncthreads();
    }
    const size_t row = row0 + t;
#pragma unroll
    for (int q = 0; q < 4; ++q)
      *(float4*)(h1 + row * 16 + q * 4) =
          make_float4(acc[q * 4], acc[q * 4 + 1], acc[q * 4 + 2], acc[q * 4 + 3]);
  } else {
    // ---------------- scatter ----------------
    const int blk = blockIdx.x - 256;
    cursor[t] = 0;
    __syncthreads();
    const int base = blk * CH;
    for (int i = 0; i < 32; ++i) {
      const int e = base + t + i * 256;
      const int s = src[e], d = dst[e];
      const float w = ew[e];
      const int b = ((unsigned)d) >> 8;
      const int pos = atomicAdd(&cursor[b], 1);
      if (pos < CAPR)
        tmp[(size_t)(b * 256 + blk) * CAPR + pos] =
            make_int2((s & 0xFFFF) | ((d & 255) << 16), __float_as_int(w));
    }
    __syncthreads();
    counts[t * 256 + blk] = cursor[t];      // bucket-major
  }
}

// ============ kernel 2: per-bucket fine sort + dinv + h1 prescale (H1 = h1*dinv) ============
__global__ __launch_bounds__(512) void ksortD(const int2* __restrict__ tmp, const int* __restrict__ counts,
                                              int2* __restrict__ csr, int* __restrict__ rs,
                                              int* __restrict__ cnt, float* __restrict__ dinv,
                                              float* __restrict__ h1) {
  __shared__ int2 stg[SCAP];                // 80 KB
  __shared__ int hist[256], excl[256], cursor[256];
  __shared__ float degacc[256], dloc[256];
  const int t = threadIdx.x, b = blockIdx.x;
  if (t < 256) { hist[t] = 0; degacc[t] = 0.f; }
  __syncthreads();
  const int seg = t >> 1, half = t & 1;
  const int len = counts[b * 256 + seg];
  const size_t cellbase = (size_t)(b * 256 + seg) * CAPR;
  // pass 1: histogram + weight-degree
  for (int i = half; i < len; i += 2) {
    const int2 p = tmp[cellbase + i];
    const int fine = (p.x >> 16) & 255;
    atomicAdd(&hist[fine], 1);
    atomicAdd(&degacc[fine], __int_as_float(p.y));
  }
  __syncthreads();
  if (t < 256) excl[t] = hist[t];
  __syncthreads();
#pragma unroll
  for (int off = 1; off < 256; off <<= 1) {
    int a = (t < 256 && t >= off) ? excl[t - off] : 0;
    __syncthreads();
    if (t < 256) excl[t] += a;              // inclusive scan
    __syncthreads();
  }
  if (t < 256) {
    const int e = excl[t] - hist[t];
    cursor[t] = e;
    rs[b * 256 + t] = b * CAPB + e;
    cnt[b * 256 + t] = hist[t];
    const float dn = rsqrtf(1.0f + degacc[t]);
    dloc[t] = dn;
    dinv[b * 256 + t] = dn;
  }
  __syncthreads();
  // pass 2: re-read (L2-warm) and place sorted into LDS
  for (int i = half; i < len; i += 2) {
    const int2 p = tmp[cellbase + i];
    const int fine = (p.x >> 16) & 255;
    const int pos = atomicAdd(&cursor[fine], 1);
    if (pos < SCAP) stg[pos] = make_int2(p.x & 0xFFFF, p.y);
  }
  __syncthreads();
  const int ntot = excl[255];
  for (int j = t; j < ntot; j += 512) csr[(size_t)b * CAPB + j] = stg[j];   // coalesced
  // prescale h1 rows of this bucket: H1 = h1 * dinv
  for (int v = t; v < 1024; v += 512) {
    const int node = v >> 2, q = v & 3;
    float* hp = h1 + (size_t)(b * 256 + node) * 16 + q * 4;
    float4 h = *(float4*)hp;
    const float dn = dloc[node];
    h.x *= dn; h.y *= dn; h.z *= dn; h.w *= dn;
    *(float4*)hp = h;
  }
}

// ============ gather layer 1: agg(H1) -> relu -> @W2 -> H2 (scaled) ============
__global__ __launch_bounds__(256) void kgather1(const float* __restrict__ H1, const int* __restrict__ rs,
                                                const int* __restrict__ cnt, const int2* __restrict__ csr,
                                                const float* __restrict__ dinv,
                                                const float* __restrict__ W2, const float* __restrict__ b1,
                                                float* __restrict__ H2) {
  __shared__ float sh_t[4][16];
  const int tid = threadIdx.x, wv = tid >> 6, l = tid & 63;
  const int n = blockIdx.x * 4 + wv;
  const int f = l & 15, slot = l >> 4;
  const int beg = rs[n], len = cnt[n];
  float acc = 0.f;
  for (int j = slot; j < len; j += 4) {
    const int2 p = csr[beg + j];
    acc = fmaf(__int_as_float(p.y), H1[(size_t)p.x * 16 + f], acc);
  }
  acc += __shfl_xor(acc, 16, 64);
  acc += __shfl_xor(acc, 32, 64);
  if (slot == 0) {
    const float dn = dinv[n];
    float t = dn * (acc + H1[(size_t)n * 16 + f]) + b1[f];
    sh_t[wv][f] = t > 0.f ? t : 0.f;
  }
  __syncthreads();
  if (tid < 16) {
    const int w2 = tid >> 2, c = tid & 3;
    const int nn = blockIdx.x * 4 + w2;
    float s = 0.f;
#pragma unroll
    for (int ff = 0; ff < 16; ++ff) s = fmaf(sh_t[w2][ff], W2[ff * 4 + c], s);
    H2[(size_t)nn * 4 + c] = s * dinv[nn];
  }
}

// ============ gather layer 2: agg(H2) -> relu -> @W3 -> H3 (scaled) ============
__global__ __launch_bounds__(256) void kgather2(const float* __restrict__ H2, const int* __restrict__ rs,
                                                const int* __restrict__ cnt, const int2* __restrict__ csr,
                                                const float* __restrict__ dinv,
                                                const float* __restrict__ W3, const float* __restrict__ b2,
                                                float* __restrict__ H3) {
  const int tid = threadIdx.x, wv = tid >> 6, l = tid & 63;
  const int n = blockIdx.x * 4 + wv;
  const int f = l & 3, slot = l >> 2;
  const int beg = rs[n], len = cnt[n];
  float acc = 0.f;
  for (int j = slot; j < len; j += 16) {
    const int2 p = csr[beg + j];
    acc = fmaf(__int_as_float(p.y), H2[(size_t)p.x * 4 + f], acc);
  }
#pragma unroll
  for (int off = 4; off < 64; off <<= 1) acc += __shfl_xor(acc, off, 64);
  const float dn = dinv[n];
  float t = dn * (acc + H2[(size_t)n * 4 + f]) + b2[f];
  t = t > 0.f ? t : 0.f;
  float p = t * W3[f];
  p += __shfl_xor(p, 1, 64);
  p += __shfl_xor(p, 2, 64);
  if (l == 0) H3[n] = p * dn;
}

// ============ gather layer 3: agg(H3) -> relu -> flat (+ seed out with bias) ============
__global__ __launch_bounds__(256) void kgather3(const float* __restrict__ H3, const int* __restrict__ rs,
                                                const int* __restrict__ cnt, const int2* __restrict__ csr,
                                                const float* __restrict__ dinv,
                                                const float* __restrict__ b3, float* __restrict__ flat,
                                                const float* __restrict__ bout, float* __restrict__ out) {
  const int tid = threadIdx.x, wv = tid >> 6, l = tid & 63;
  if (blockIdx.x == 0 && tid < NB) out[tid] = bout[tid];
  const int n = blockIdx.x * 4 + wv;
  const int beg = rs[n], len = cnt[n];
  float acc = 0.f;
  for (int j = l; j < len; j += 64) {
    const int2 p = csr[beg + j];
    acc = fmaf(__int_as_float(p.y), H3[p.x], acc);
  }
#pragma unroll
  for (int off = 1; off < 64; off <<= 1) acc += __shfl_xor(acc, off, 64);
  if (l == 0) {
    const float dn = dinv[n];
    float t = dn * (acc + H3[n]) + b3[0];
    flat[n] = t > 0.f ? t : 0.f;
  }
}

// ============ final dense: out[b] += partial dot(flat, W_out[b,:]) ============
__global__ __launch_bounds__(256) void kfinal(const float* __restrict__ flat, const float* __restrict__ Wout,
                                              float* __restrict__ out) {
  const int b = blockIdx.x >> 2, q = blockIdx.x & 3;
  const float4* __restrict__ f4 = (const float4*)(flat) + q * 4096;
  const float4* __restrict__ w4 = (const float4*)(Wout + (size_t)b * NNODES) + q * 4096;
  float s = 0.f;
  for (int i = threadIdx.x; i < 4096; i += 256) {
    const float4 a = f4[i];
    const float4 wv = w4[i];
    s += a.x * wv.x + a.y * wv.y + a.z * wv.z + a.w * wv.w;
  }
#pragma unroll
  for (int off = 32; off; off >>= 1) s += __shfl_down(s, off, 64);
  __shared__ float red[4];
  if ((threadIdx.x & 63) == 0) red[threadIdx.x >> 6] = s;
  __syncthreads();
  if (threadIdx.x == 0) atomicAdd(&out[b], red[0] + red[1] + red[2] + red[3]);
}

extern "C" void kernel_launch(void* const* d_in, const int* in_sizes, int n_in,
                              void* d_out, int out_size, void* d_ws, size_t ws_size,
                              hipStream_t stream) {
  const float* x   = (const float*)d_in[0];
  const int*   A   = (const int*)d_in[1];
  const float* ew  = (const float*)d_in[2];
  const float* W1  = (const float*)d_in[3];
  const float* b1  = (const float*)d_in[4];
  const float* W2  = (const float*)d_in[5];
  const float* b2  = (const float*)d_in[6];
  const float* W3  = (const float*)d_in[7];
  const float* b3  = (const float*)d_in[8];
  const float* Wo  = (const float*)d_in[9];
  const float* bo  = (const float*)d_in[10];
  float* out = (float*)d_out;

  const int* src = A;
  const int* dst = A + NEDGES;

  // ---- workspace layout ----
  char* p = (char*)d_ws;
  float* dinv   = (float*)p; p += sizeof(float) * NNODES;
  int*   rsofs  = (int*)p;   p += sizeof(int) * NNODES;
  int*   cnt    = (int*)p;   p += sizeof(int) * NNODES;
  int*   counts = (int*)p;   p += sizeof(int) * NNODES;
  int2*  tmp    = (int2*)p;  p += sizeof(int2) * (size_t)NNODES * CAPR;   // 50.3 MB
  int2*  csr    = (int2*)p;  p += sizeof(int2) * (size_t)G * CAPB;        // 18.9 MB
  float* h1     = (float*)p; p += sizeof(float) * (size_t)NNODES * 16;
  float* H2     = (float*)p; p += sizeof(float) * (size_t)NNODES * 4;
  float* H3     = (float*)p; p += sizeof(float) * NNODES;
  float* flat   = (float*)p; p += sizeof(float) * NNODES;

  kmain<<<512, 256, 0, stream>>>(x, W1, h1, src, dst, ew, tmp, counts);
  ksortD<<<G, 512, 0, stream>>>(tmp, counts, csr, rsofs, cnt, dinv, h1);
  kgather1<<<NNODES / 4, 256, 0, stream>>>(h1, rsofs, cnt, csr, dinv, W2, b1, H2);
  kgather2<<<NNODES / 4, 256, 0, stream>>>(H2, rsofs, cnt, csr, dinv, W3, b2, H3);
  kgather3<<<NNODES / 4, 256, 0, stream>>>(H3, rsofs, cnt, csr, dinv, b3, flat, bo, out);
  kfinal<<<NB * 4, 256, 0, stream>>>(flat, Wo, out);
}

// Round 10
// 239.712 us; speedup vs baseline: 1.4478x; 1.4478x over previous
//
#include <hip/hip_runtime.h>

#define NNODES 65536
#define FIN 1024
#define NEDGES 2097152
#define NB 64
#define G 256                 // buckets = dst>>8
#define CH (NEDGES / G)       // 8192 edges per scatter block
#define CAP 10240             // LDS staging capacity in ksortC (80 KB)
#define NR 20                 // reg-staged edges per thread in ksortC
#define GEMMB 256             // gemm blocks in fused kernel A (256 rows each)

// ============ kernel A: fused  h1 = x@W1 (unscaled)  ∪  coarse histogram ============
// gemm: 512 thr = 64 rg x 4 jg x 2 ks. Thread: 4 rows (rg+64*ri) x 4 cols (jg*4..) over
// its k-half. LDS x tile [2][256][20] (b128-aligned, bank-spread), W tile [2][16][16].
// 2 B LDS per FMA (vs 5 in round 8). ks-halves reduced via LDS at the end.
__global__ __launch_bounds__(512) void khistgemm(const float* __restrict__ x, const float* __restrict__ W1,
                                                 float* __restrict__ h1, const int* __restrict__ dst,
                                                 int* __restrict__ counts) {
  __shared__ float sxf[2 * 256 * 20];       // 40 KB
  __shared__ float swf[2 * 16 * 16];        // 2 KB
  __shared__ int hist[256];
  const int t = threadIdx.x;
  if (blockIdx.x < GEMMB) {
    // ---------------- GEMM: 256 rows ----------------
    const int jg = t & 3, ks = (t >> 2) & 1, rg = t >> 3;
    const int row0 = blockIdx.x * 256;
    float4 acc4[4];
#pragma unroll
    for (int ri = 0; ri < 4; ++ri) acc4[ri] = make_float4(0.f, 0.f, 0.f, 0.f);

    for (int ch = 0; ch < 32; ++ch) {
      // stage x: 2048 float4 (2 k-regions x 256 rows x 16 k), coalesced
#pragma unroll
      for (int i = 0; i < 4; ++i) {
        const int v = t + i * 512;
        const int reg = v >> 10, idx = v & 1023;
        const int rr = idx >> 2, k4 = idx & 3;
        const float4 xv =
            *(const float4*)(x + (size_t)(row0 + rr) * FIN + (reg * 32 + ch) * 16 + k4 * 4);
        *(float4*)&sxf[reg * 5120 + rr * 20 + k4 * 4] = xv;
      }
      if (t < 128) {                        // stage W: 2 regions x 16 k x 16 cols
        const int reg = t >> 6, idx = t & 63;
        const int kk = idx >> 2, c4 = idx & 3;
        *(float4*)&swf[reg * 256 + kk * 16 + c4 * 4] =
            *(const float4*)(W1 + (size_t)((reg * 32 + ch) * 16 + kk) * 16 + c4 * 4);
      }
      __syncthreads();
      const int xb = ks * 5120 + rg * 20;
      const int wb = ks * 256 + jg * 4;
#pragma unroll
      for (int k4 = 0; k4 < 4; ++k4) {
        float4 w4[4];
#pragma unroll
        for (int kq = 0; kq < 4; ++kq) w4[kq] = *(const float4*)&swf[wb + (k4 * 4 + kq) * 16];
#pragma unroll
        for (int ri = 0; ri < 4; ++ri) {
          const float4 x4 = *(const float4*)&sxf[xb + ri * 1280 + k4 * 4];
          acc4[ri].x = fmaf(x4.x, w4[0].x, fmaf(x4.y, w4[1].x, fmaf(x4.z, w4[2].x, fmaf(x4.w, w4[3].x, acc4[ri].x))));
          acc4[ri].y = fmaf(x4.x, w4[0].y, fmaf(x4.y, w4[1].y, fmaf(x4.z, w4[2].y, fmaf(x4.w, w4[3].y, acc4[ri].y))));
          acc4[ri].z = fmaf(x4.x, w4[0].z, fmaf(x4.y, w4[1].z, fmaf(x4.z, w4[2].z, fmaf(x4.w, w4[3].z, acc4[ri].z))));
          acc4[ri].w = fmaf(x4.x, w4[0].w, fmaf(x4.y, w4[1].w, fmaf(x4.z, w4[2].w, fmaf(x4.w, w4[3].w, acc4[ri].w))));
        }
      }
      __syncthreads();
    }
    // ks-pair reduction via LDS, then write h1
    if (ks == 1) {
      float* slot = &sxf[(rg * 4 + jg) * 16];
#pragma unroll
      for (int ri = 0; ri < 4; ++ri) *(float4*)(slot + ri * 4) = acc4[ri];
    }
    __syncthreads();
    if (ks == 0) {
      const float* slot = &sxf[(rg * 4 + jg) * 16];
#pragma unroll
      for (int ri = 0; ri < 4; ++ri) {
        const float4 o = *(const float4*)(slot + ri * 4);
        float4 s = acc4[ri];
        s.x += o.x; s.y += o.y; s.z += o.z; s.w += o.w;
        *(float4*)(h1 + (size_t)(row0 + rg + ri * 64) * 16 + jg * 4) = s;
      }
    }
  } else {
    // ---------------- histogram ----------------
    const int blk = blockIdx.x - GEMMB;
    if (t < 256) hist[t] = 0;
    __syncthreads();
    const int base = blk * CH;
    for (int i = t; i < CH; i += 512) atomicAdd(&hist[((unsigned)dst[base + i]) >> 8], 1);
    __syncthreads();
    if (t < 256) counts[t * G + blk] = hist[t];   // bucket-major, block-minor
  }
}

// ============ kernel B: scatter with redundant in-block scan (round 8, unchanged) ============
__global__ __launch_bounds__(1024) void kscatter3(const int* __restrict__ src, const int* __restrict__ dst,
                                                  const float* __restrict__ ew, const int* __restrict__ counts,
                                                  int2* __restrict__ tmp, int* __restrict__ bucketofs) {
  __shared__ int2 ent[CH];                  // 64 KB
  __shared__ int hist[256], excl[256], cursor[256], ldsofs[256], sh[256];
  __shared__ int wsum[16];
  const int t = threadIdx.x, blk = blockIdx.x;
  const int lane = t & 63, wid = t >> 6;

  int4 v[16];
  {
    const int4* __restrict__ ip = (const int4*)(counts + t * 64);
    int s = 0;
#pragma unroll
    for (int i = 0; i < 16; ++i) { v[i] = ip[i]; s += v[i].x + v[i].y + v[i].z + v[i].w; }
    int inc = s;
#pragma unroll
    for (int off = 1; off < 64; off <<= 1) {
      int o = __shfl_up(inc, off, 64);
      if (lane >= off) inc += o;
    }
    if (lane == 63) wsum[wid] = inc;
    __syncthreads();
    if (t < 16) {
      int w = wsum[t];
      int wi = w;
#pragma unroll
      for (int off = 1; off < 16; off <<= 1) {
        int o = __shfl_up(wi, off, 16);
        if (t >= off) wi += o;
      }
      wsum[t] = wi - w;
    }
    __syncthreads();
    int run = inc - s + wsum[wid];
    const int j0 = (blk - t * 64) & 255;
#pragma unroll
    for (int i = 0; i < 16; ++i) {
      const int vals[4] = {v[i].x, v[i].y, v[i].z, v[i].w};
#pragma unroll
      for (int q = 0; q < 4; ++q) {
        const int j = i * 4 + q;
        if (j == j0) {
          const int c = t * 64 + j;
          ldsofs[c >> 8] = run;
          hist[c >> 8] = vals[q];
        }
        run += vals[q];
      }
    }
  }
  __syncthreads();
  if (blk == 0) {
    if (t < 256) bucketofs[t] = ldsofs[t];
    if (t == 0) bucketofs[256] = NEDGES;
  }
  if (t < 256) sh[t] = hist[t];
  __syncthreads();
#pragma unroll
  for (int off = 1; off < 256; off <<= 1) {
    int a = (t < 256 && t >= off) ? sh[t - off] : 0;
    __syncthreads();
    if (t < 256) sh[t] += a;
    __syncthreads();
  }
  if (t < 256) { excl[t] = sh[t] - hist[t]; cursor[t] = sh[t] - hist[t]; }
  __syncthreads();
  int sa[8], da[8]; float wa[8];
  const int base = blk * CH;
#pragma unroll
  for (int i = 0; i < 8; ++i) {
    const int e = base + t + i * 1024;
    sa[i] = src[e]; da[i] = dst[e]; wa[i] = ew[e];
  }
#pragma unroll
  for (int i = 0; i < 8; ++i) {
    const int b = ((unsigned)da[i]) >> 8;
    const int pos = atomicAdd(&cursor[b], 1);
    ent[pos] = make_int2((sa[i] & 0xFFFF) | ((da[i] & 255) << 16) | (b << 24), __float_as_int(wa[i]));
  }
  __syncthreads();
#pragma unroll
  for (int i = 0; i < 8; ++i) {
    const int idx = t + i * 1024;
    const int2 p = ent[idx];
    const int b = ((unsigned)p.x) >> 24;
    tmp[ldsofs[b] + (idx - excl[b])] = make_int2(p.x & 0x00FFFFFF, p.y);
  }
}

// ============ kernel C: per-bucket fine sort (round 8, unchanged) ============
__global__ __launch_bounds__(512) void ksortC(const int2* __restrict__ tmp, const int* __restrict__ bucketofs,
                                              int2* __restrict__ csr, int* __restrict__ rs,
                                              int* __restrict__ cnt, float* __restrict__ dinv) {
  __shared__ int2 stg[CAP];                 // 80 KB
  __shared__ int hist[256], excl[256], cursor[256];
  __shared__ float degacc[256];
  const int t = threadIdx.x, b = blockIdx.x;
  const int base = bucketofs[b];
  const int end = bucketofs[b + 1];
  const int n = end - base;
  if (t < 256) { hist[t] = 0; degacc[t] = 0.f; }
  __syncthreads();
  int2 r[NR];
#pragma unroll
  for (int i = 0; i < NR; ++i) {
    const int idx = i * 512 + t;
    if (idx < n) r[i] = tmp[base + idx];
  }
#pragma unroll
  for (int i = 0; i < NR; ++i) {
    const int idx = i * 512 + t;
    if (idx < n) atomicAdd(&hist[(r[i].x >> 16) & 255], 1);
  }
  __syncthreads();
  if (t < 256) excl[t] = hist[t];
  __syncthreads();
#pragma unroll
  for (int off = 1; off < 256; off <<= 1) {
    int a = (t < 256 && t >= off) ? excl[t - off] : 0;
    __syncthreads();
    if (t < 256) excl[t] += a;
    __syncthreads();
  }
  if (t < 256) {
    const int e = excl[t] - hist[t];
    cursor[t] = e;
    rs[b * 256 + t] = base + e;
    cnt[b * 256 + t] = hist[t];
  }
  __syncthreads();
#pragma unroll
  for (int i = 0; i < NR; ++i) {
    const int idx = i * 512 + t;
    if (idx < n) {
      const int fine = (r[i].x >> 16) & 255;
      const int pos = atomicAdd(&cursor[fine], 1);
      const int2 rec = make_int2(r[i].x & 0xFFFF, r[i].y);
      if (pos < CAP) stg[pos] = rec;
      else csr[base + pos] = rec;
      atomicAdd(&degacc[fine], __int_as_float(r[i].y));
    }
  }
  __syncthreads();
  if (t < 256) dinv[b * 256 + t] = rsqrtf(1.0f + degacc[t]);
  const int m = n < CAP ? n : CAP;
  for (int j = t; j < m; j += 512) csr[base + j] = stg[j];
}

// ============ gather layer 1 (round 8, unchanged) ============
__global__ __launch_bounds__(256) void kgather1(const float* __restrict__ h1, const int* __restrict__ rs,
                                                const int* __restrict__ cnt, const int2* __restrict__ csr,
                                                const float* __restrict__ dinv,
                                                const float* __restrict__ W2, const float* __restrict__ b1,
                                                float* __restrict__ H2) {
  __shared__ float sh_t[4][16];
  const int tid = threadIdx.x, wv = tid >> 6, l = tid & 63;
  const int n = blockIdx.x * 4 + wv;
  const int f = l & 15, slot = l >> 4;
  const int beg = rs[n], len = cnt[n];
  float acc = 0.f;
  for (int j = slot; j < len; j += 4) {
    const int2 p = csr[beg + j];
    acc = fmaf(__int_as_float(p.y) * dinv[p.x], h1[(size_t)p.x * 16 + f], acc);
  }
  acc += __shfl_xor(acc, 16, 64);
  acc += __shfl_xor(acc, 32, 64);
  if (slot == 0) {
    const float dn = dinv[n];
    float t = dn * (acc + dn * h1[(size_t)n * 16 + f]) + b1[f];
    sh_t[wv][f] = t > 0.f ? t : 0.f;
  }
  __syncthreads();
  if (tid < 16) {
    const int w2 = tid >> 2, c = tid & 3;
    const int nn = blockIdx.x * 4 + w2;
    float s = 0.f;
#pragma unroll
    for (int ff = 0; ff < 16; ++ff) s = fmaf(sh_t[w2][ff], W2[ff * 4 + c], s);
    H2[(size_t)nn * 4 + c] = s * dinv[nn];
  }
}

// ============ gather layer 2 (round 8, unchanged) ============
__global__ __launch_bounds__(256) void kgather2(const float* __restrict__ H2, const int* __restrict__ rs,
                                                const int* __restrict__ cnt, const int2* __restrict__ csr,
                                                const float* __restrict__ dinv,
                                                const float* __restrict__ W3, const float* __restrict__ b2,
                                                float* __restrict__ H3) {
  const int tid = threadIdx.x, wv = tid >> 6, l = tid & 63;
  const int n = blockIdx.x * 4 + wv;
  const int f = l & 3, slot = l >> 2;
  const int beg = rs[n], len = cnt[n];
  float acc = 0.f;
  for (int j = slot; j < len; j += 16) {
    const int2 p = csr[beg + j];
    acc = fmaf(__int_as_float(p.y), H2[(size_t)p.x * 4 + f], acc);
  }
#pragma unroll
  for (int off = 4; off < 64; off <<= 1) acc += __shfl_xor(acc, off, 64);
  const float dn = dinv[n];
  float t = dn * (acc + H2[(size_t)n * 4 + f]) + b2[f];
  t = t > 0.f ? t : 0.f;
  float p = t * W3[f];
  p += __shfl_xor(p, 1, 64);
  p += __shfl_xor(p, 2, 64);
  if (l == 0) H3[n] = p * dn;
}

// ============ gather layer 3 (round 8, unchanged) ============
__global__ __launch_bounds__(256) void kgather3(const float* __restrict__ H3, const int* __restrict__ rs,
                                                const int* __restrict__ cnt, const int2* __restrict__ csr,
                                                const float* __restrict__ dinv,
                                                const float* __restrict__ b3, float* __restrict__ flat,
                                                const float* __restrict__ bout, float* __restrict__ out) {
  const int tid = threadIdx.x, wv = tid >> 6, l = tid & 63;
  if (blockIdx.x == 0 && tid < NB) out[tid] = bout[tid];
  const int n = blockIdx.x * 4 + wv;
  const int beg = rs[n], len = cnt[n];
  float acc = 0.f;
  for (int j = l; j < len; j += 64) {
    const int2 p = csr[beg + j];
    acc = fmaf(__int_as_float(p.y), H3[p.x], acc);
  }
#pragma unroll
  for (int off = 1; off < 64; off <<= 1) acc += __shfl_xor(acc, off, 64);
  if (l == 0) {
    const float dn = dinv[n];
    float t = dn * (acc + H3[n]) + b3[0];
    flat[n] = t > 0.f ? t : 0.f;
  }
}

// ============ final dense (round 8, unchanged) ============
__global__ __launch_bounds__(256) void kfinal(const float* __restrict__ flat, const float* __restrict__ Wout,
                                              float* __restrict__ out) {
  const int b = blockIdx.x >> 2, q = blockIdx.x & 3;
  const float4* __restrict__ f4 = (const float4*)(flat) + q * 4096;
  const float4* __restrict__ w4 = (const float4*)(Wout + (size_t)b * NNODES) + q * 4096;
  float s = 0.f;
  for (int i = threadIdx.x; i < 4096; i += 256) {
    const float4 a = f4[i];
    const float4 wv = w4[i];
    s += a.x * wv.x + a.y * wv.y + a.z * wv.z + a.w * wv.w;
  }
#pragma unroll
  for (int off = 32; off; off >>= 1) s += __shfl_down(s, off, 64);
  __shared__ float red[4];
  if ((threadIdx.x & 63) == 0) red[threadIdx.x >> 6] = s;
  __syncthreads();
  if (threadIdx.x == 0) atomicAdd(&out[b], red[0] + red[1] + red[2] + red[3]);
}

extern "C" void kernel_launch(void* const* d_in, const int* in_sizes, int n_in,
                              void* d_out, int out_size, void* d_ws, size_t ws_size,
                              hipStream_t stream) {
  const float* x   = (const float*)d_in[0];
  const int*   A   = (const int*)d_in[1];
  const float* ew  = (const float*)d_in[2];
  const float* W1  = (const float*)d_in[3];
  const float* b1  = (const float*)d_in[4];
  const float* W2  = (const float*)d_in[5];
  const float* b2  = (const float*)d_in[6];
  const float* W3  = (const float*)d_in[7];
  const float* b3  = (const float*)d_in[8];
  const float* Wo  = (const float*)d_in[9];
  const float* bo  = (const float*)d_in[10];
  float* out = (float*)d_out;

  const int* src = A;
  const int* dst = A + NEDGES;

  // ---- workspace layout ----
  char* p = (char*)d_ws;
  float* dinv      = (float*)p; p += sizeof(float) * NNODES;
  int*   rsofs     = (int*)p;   p += sizeof(int) * NNODES;
  int*   cnt       = (int*)p;   p += sizeof(int) * NNODES;
  int*   counts    = (int*)p;   p += sizeof(int) * 256 * G;
  int*   bucketofs = (int*)p;   p += sizeof(int) * 260;
  int2*  tmp       = (int2*)p;  p += sizeof(int2) * NEDGES;
  int2*  csr       = (int2*)p;  p += sizeof(int2) * NEDGES;
  float* h1        = (float*)p; p += sizeof(float) * (size_t)NNODES * 16;
  float* H2        = (float*)p; p += sizeof(float) * (size_t)NNODES * 4;
  float* H3        = (float*)p; p += sizeof(float) * NNODES;
  float* flat      = (float*)p; p += sizeof(float) * NNODES;

  khistgemm<<<GEMMB + G, 512, 0, stream>>>(x, W1, h1, dst, counts);
  kscatter3<<<G, 1024, 0, stream>>>(src, dst, ew, counts, tmp, bucketofs);
  ksortC<<<G, 512, 0, stream>>>(tmp, bucketofs, csr, rsofs, cnt, dinv);
  kgather1<<<NNODES / 4, 256, 0, stream>>>(h1, rsofs, cnt, csr, dinv, W2, b1, H2);
  kgather2<<<NNODES / 4, 256, 0, stream>>>(H2, rsofs, cnt, csr, dinv, W3, b2, H3);
  kgather3<<<NNODES / 4, 256, 0, stream>>>(H3, rsofs, cnt, csr, dinv, b3, flat, bo, out);
  kfinal<<<NB * 4, 256, 0, stream>>>(flat, Wo, out);
}